// Round 14
// baseline (36.264 us; speedup 1.0000x reference)
//
#include <hip/hip_runtime.h>
#include <stdint.h>

typedef __attribute__((ext_vector_type(8))) short short8;
typedef __attribute__((ext_vector_type(4))) float f32x4;

#define DEVI __device__ __forceinline__

DEVI ushort f2bf(float f) {
  union { float f; uint32_t u; } v; v.f = f;
  uint32_t r = v.u + 0x7fffu + ((v.u >> 16) & 1u);
  return (ushort)(r >> 16);
}

// HW packed f32->bf16 (RTNE, identical rounding to f2bf): 1 inst per 2 elems.
DEVI uint32_t cvtpk(float lo, float hi) {
  uint32_t r;
  asm("v_cvt_pk_bf16_f32 %0, %1, %2" : "=v"(r) : "v"(lo), "v"(hi));
  return r;
}
DEVI uint2 pack4(float a, float b, float c, float d) {
  uint2 o; o.x = cvtpk(a, b); o.y = cvtpk(c, d);
  return o;
}

// ---------------------------------------------------------------------------
// Quantum sim collapses analytically (params provably dead):
//   feats per 2x2 patch (v0,v1,v2,v3) = [cos v0, cos v1, cos v0*cos v2,
//   cos v1*cos v3]; CNOT chains = linear bit map; RZ phases cancel in |.|^2.
//
// Single-launch mega, rebuilt with R12's proven fixes for R6's disease:
//   - BM=16 rows/block, BN=256 (full N): 512 blocks x 512 thr (8 waves),
//     LDS 78.3KB -> 2 blocks/CU = 4 waves/SIMD (R6 had 2: latency-starved).
//   - cvt_pk staging (R6 used 5-op emulated casts).
// Structural wins vs two-kernel champion: x read exactly once (vs 4x), cos
// once, no h1 HBM round-trip, no second launch. Cost: W1 f32 streamed from
// XCD-resident L2 by every block (421MB aggregate ~ 12us at L2 BW).
//   Phase 1: h1(16x256) = relu(feats(x) @ W1^T + b1) -> LDS bf16
//   Phase 2: h2(16x128) = relu(h1 @ W2^T + b2)       -> regs -> LDS f32
//   Phase 3: logits = h2 @ W3^T + b3; log_softmax    -> out
// Overlays (all barrier-separated): h1t = Bs[0] rows 128+, W3s+h2f = Bs[1]
// rows 128+. Staging only ever touches Bs rows 0..127 in phase 2.
// ---------------------------------------------------------------------------
#define LDA 72     // staging stride (ushort): 144B -> conflict-free b128
#define H1LD 264   // h1 tile stride (ushort): 528B -> <=2-way (free)

__global__ __launch_bounds__(512, 4) void mega3_kernel(
    const float* __restrict__ x, const float* __restrict__ W1,
    const float* __restrict__ b1, const float* __restrict__ W2,
    const float* __restrict__ b2, const float* __restrict__ W3,
    const float* __restrict__ b3, float* __restrict__ out) {
  __shared__ __align__(16) ushort As[2][16 * LDA];    //  4608 B
  __shared__ __align__(16) ushort Bs[2][256 * LDA];   // 73728 B (78336 total)

  ushort* h1t = &Bs[0][128 * LDA];                    // 16 x 264 (8448 B)
  float* W3s = (float*)&Bs[1][128 * LDA];             // 1280 f32 (5120 B)
  float* h2f = (float*)&Bs[1][128 * LDA + 2560];      // 16 x 132 f32 (8448 B)

  const int tid = threadIdx.x;
  const int lane = tid & 63;
  const int w = tid >> 6;               // 8 waves
  const int m0 = blockIdx.x * 16;

  const int arow = tid >> 4, pl = tid & 15;   // A staging (tid<256)

  // ---------------- Phase 1: h1 = relu(feats @ W1^T + b1) ----------------
  float2 atop, abot;
  float4 bw[8];

  auto loadT1 = [&](int kt) {
    if (tid < 256) {
      const int q = kt * 16 + pl;
      if (q < 196) {
        const int i = q / 14, j = q - i * 14;
        const float* p = x + (size_t)(m0 + arow) * 784 + i * 56 + j * 2;
        atop = *(const float2*)p;
        abot = *(const float2*)(p + 28);
      }
    }
    const int k0 = kt * 64;
#pragma unroll
    for (int c = 0; c < 8; ++c) {
      const int flat = c * 512 + tid, r = flat >> 4, sl = flat & 15;
      if (k0 + sl * 4 < 784)
        bw[c] = *(const float4*)(W1 + (size_t)r * 784 + k0 + sl * 4);
      else
        bw[c] = make_float4(0.f, 0.f, 0.f, 0.f);
    }
  };
  auto writeT1 = [&](int buf, int kt) {
    if (tid < 256) {
      const int q = kt * 16 + pl;
      if (q < 196) {
        float c0 = __cosf(atop.x), c1 = __cosf(atop.y);
        float c2 = __cosf(abot.x), c3 = __cosf(abot.y);
        *(uint2*)(&As[buf][arow * LDA + pl * 4]) = pack4(c0, c1, c0 * c2, c1 * c3);
      } else {
        uint2 z; z.x = 0; z.y = 0;
        *(uint2*)(&As[buf][arow * LDA + pl * 4]) = z;
      }
    }
#pragma unroll
    for (int c = 0; c < 8; ++c) {
      const int flat = c * 512 + tid, r = flat >> 4, sl = flat & 15;
      *(uint2*)(&Bs[buf][r * LDA + sl * 4]) =
          pack4(bw[c].x, bw[c].y, bw[c].z, bw[c].w);
    }
  };

  f32x4 acc[2];                     // wave tile 16 x 32 (cols w*32)
#pragma unroll
  for (int n = 0; n < 2; ++n) {
    f32x4 z = {0.f, 0.f, 0.f, 0.f};
    acc[n] = z;
  }

  auto mma1 = [&](int buf) {
#pragma unroll
    for (int ks = 0; ks < 2; ++ks) {
      short8 af = *(const short8*)(&As[buf][(lane & 15) * LDA + ks * 32 + (lane >> 4) * 8]);
#pragma unroll
      for (int n = 0; n < 2; ++n) {
        const int cdx = w * 32 + n * 16 + (lane & 15);
        short8 bf = *(const short8*)(&Bs[buf][cdx * LDA + ks * 32 + (lane >> 4) * 8]);
        acc[n] = __builtin_amdgcn_mfma_f32_16x16x32_bf16(af, bf, acc[n], 0, 0, 0);
      }
    }
  };

  loadT1(0);
  writeT1(0, 0);
  __syncthreads();
  int cur = 0;
  for (int kt = 0; kt < 13; ++kt) {
    if (kt + 1 < 13) loadT1(kt + 1);
    mma1(cur);
    if (kt + 1 < 13) writeT1(cur ^ 1, kt + 1);
    __syncthreads();
    cur ^= 1;
  }

  // epilogue: h1 tile -> LDS bf16 (bias+relu); W3 -> LDS; issue W2 prefetch.
  // C/D layout: col = lane&15, row = (lane>>4)*4 + reg   [m89-verified]
#pragma unroll
  for (int n = 0; n < 2; ++n) {
    const int col = w * 32 + n * 16 + (lane & 15);
    const float bval = b1[col];
#pragma unroll
    for (int r = 0; r < 4; ++r) {
      const int row = (lane >> 4) * 4 + r;
      h1t[row * H1LD + col] = f2bf(fmaxf(acc[n][r] + bval, 0.f));
    }
  }
  for (int i = tid; i < 1280; i += 512) W3s[i] = W3[i];

  // ---------------- Phase 2: h2 = relu(h1 @ W2^T + b2) ----------------
  float4 bw2[4];
  auto loadB2 = [&](int kt) {
    const int k0 = kt * 64;
#pragma unroll
    for (int c = 0; c < 4; ++c) {
      const int flat = c * 512 + tid, r = flat >> 4, sl = flat & 15;
      bw2[c] = *(const float4*)(W2 + (size_t)r * 256 + k0 + sl * 4);
    }
  };
  auto writeB2 = [&](int buf) {
#pragma unroll
    for (int c = 0; c < 4; ++c) {
      const int flat = c * 512 + tid, r = flat >> 4, sl = flat & 15;
      *(uint2*)(&Bs[buf][r * LDA + sl * 4]) =
          pack4(bw2[c].x, bw2[c].y, bw2[c].z, bw2[c].w);
    }
  };

  f32x4 acc2;
  {
    f32x4 z = {0.f, 0.f, 0.f, 0.f};
    acc2 = z;
  }
  auto mma2 = [&](int buf, int kt) {
#pragma unroll
    for (int ks = 0; ks < 2; ++ks) {
      short8 af = *(const short8*)(&h1t[(lane & 15) * H1LD + kt * 64 + ks * 32 + (lane >> 4) * 8]);
      const int cdx = w * 16 + (lane & 15);
      short8 bf = *(const short8*)(&Bs[buf][cdx * LDA + ks * 32 + (lane >> 4) * 8]);
      acc2 = __builtin_amdgcn_mfma_f32_16x16x32_bf16(af, bf, acc2, 0, 0, 0);
    }
  };

  // phase-1 loop ended with a barrier -> Bs lower halves are free to stage.
  loadB2(0);
  writeB2(0);
  __syncthreads();    // h1t + W3s + Bs[0]-lower all visible
#pragma unroll
  for (int kt = 0; kt < 4; ++kt) {
    if (kt < 3) loadB2(kt + 1);
    mma2(kt & 1, kt);
    if (kt < 3) writeB2((kt + 1) & 1);
    __syncthreads();
  }

  // h2 -> LDS f32 (upper Bs[1], after W3s; last mma2 read Bs[1] lower only)
  {
    const int col = w * 16 + (lane & 15);
    const float bval = b2[col];
#pragma unroll
    for (int r = 0; r < 4; ++r)
      h2f[((lane >> 4) * 4 + r) * 132 + col] = fmaxf(acc2[r] + bval, 0.f);
  }
  __syncthreads();

  // ---------------- Phase 3: head (logits + log_softmax) ----------------
  {
    const int r = tid >> 5, p = tid & 31;   // 16 rows x 32 partials
    float a10[10];
#pragma unroll
    for (int n = 0; n < 10; ++n) a10[n] = 0.f;
#pragma unroll
    for (int e = 0; e < 4; ++e) {
      const int k = e * 32 + p;
      const float hv = h2f[r * 132 + k];
#pragma unroll
      for (int n = 0; n < 10; ++n) a10[n] = fmaf(hv, W3s[n * 128 + k], a10[n]);
    }
#pragma unroll
    for (int n = 0; n < 10; ++n) {
      a10[n] += __shfl_xor(a10[n], 1);
      a10[n] += __shfl_xor(a10[n], 2);
      a10[n] += __shfl_xor(a10[n], 4);
      a10[n] += __shfl_xor(a10[n], 8);
      a10[n] += __shfl_xor(a10[n], 16);
    }
    if (p == 0) {
#pragma unroll
      for (int n = 0; n < 10; ++n) a10[n] += b3[n];
      float mx = a10[0];
#pragma unroll
      for (int n = 1; n < 10; ++n) mx = fmaxf(mx, a10[n]);
      float s = 0.f;
#pragma unroll
      for (int n = 0; n < 10; ++n) s += __expf(a10[n] - mx);
      const float lse = mx + __logf(s);
      float* po = out + (size_t)(m0 + r) * 10;
#pragma unroll
      for (int n = 0; n < 10; ++n) po[n] = a10[n] - lse;
    }
  }
}

// ---------------------------------------------------------------------------
extern "C" void kernel_launch(void* const* d_in, const int* in_sizes, int n_in,
                              void* d_out, int out_size, void* d_ws, size_t ws_size,
                              hipStream_t stream) {
  const float* x  = (const float*)d_in[0];   // (8192,1,28,28)
  // d_in[1] = params: provably unused (diagonal phases cancel in |amp|^2)
  const float* W1 = (const float*)d_in[2];
  const float* b1 = (const float*)d_in[3];
  const float* W2 = (const float*)d_in[4];
  const float* b2 = (const float*)d_in[5];
  const float* W3 = (const float*)d_in[6];
  const float* b3 = (const float*)d_in[7];
  float* out = (float*)d_out;

  hipLaunchKernelGGL(mega3_kernel, dim3(512), dim3(512), 0, stream,
                     x, W1, b1, W2, b2, W3, b3, out);
}

// Round 16
// 27.815 us; speedup vs baseline: 1.3037x; 1.3037x over previous
//
#include <hip/hip_runtime.h>
#include <stdint.h>

typedef __attribute__((ext_vector_type(8))) short short8;
typedef __attribute__((ext_vector_type(4))) float f32x4;

#define DEVI __device__ __forceinline__

DEVI ushort f2bf(float f) {
  union { float f; uint32_t u; } v; v.f = f;
  uint32_t r = v.u + 0x7fffu + ((v.u >> 16) & 1u);
  return (ushort)(r >> 16);
}

// HW packed f32->bf16 (RTNE, identical rounding to f2bf): 1 inst per 2 elems.
DEVI uint32_t cvtpk(float lo, float hi) {
  uint32_t r;
  asm("v_cvt_pk_bf16_f32 %0, %1, %2" : "=v"(r) : "v"(lo), "v"(hi));
  return r;
}
DEVI uint2 pack4(float a, float b, float c, float d) {
  uint2 o; o.x = cvtpk(a, b); o.y = cvtpk(c, d);
  return o;
}

// ---------------------------------------------------------------------------
// Quantum sim collapses analytically (params provably dead):
//   feats per 2x2 patch (v0,v1,v2,v3) = [cos v0, cos v1, cos v0*cos v2,
//   cos v1*cos v3]; CNOT chains = linear bit map; RZ phases cancel in |.|^2.
//
// Kernel 1 (R12 champion, byte-identical): h1 = relu(feats(x) @ W1^T + b1),
// cos + W1 cast fused into staging. BM=BN=64, BK=64, dbuf, 512 blocks x
// 512 threads (8 waves) = 4 waves/SIMD.
// ---------------------------------------------------------------------------
__global__ __launch_bounds__(512) void gemm1_fused(
    const float* __restrict__ x, const float* __restrict__ W1,
    const float* __restrict__ b1, ushort* __restrict__ h1) {
  constexpr int LDA = 72;   // 144B row stride -> <=2-way b128 reads (free)
  constexpr int NK = 13;    // K = 832 (784 + pad)
  __shared__ ushort As[2][64 * LDA];   // 18432 B
  __shared__ ushort Bs[2][64 * LDA];   // 18432 B  (36864 total)

  const int tid = threadIdx.x;
  const int lane = tid & 63;
  const int w = tid >> 6;              // 8 waves: wm in {0,1}, wn in {0..3}
  const int wm = w >> 2, wn = w & 3;
  const int bm = blockIdx.x & 127, bn = blockIdx.x >> 7;
  const int m0 = bm * 64, n0 = bn * 64;

  const int srow = tid >> 4;        // 0..31: staging row within 32-row group
  const int pl = tid & 15;          // patch slot / float4 slot
  const int kc4 = pl * 4;

  float2 atop[2], abot[2];          // staged x (2 rows, 1 patch)
  float4 bw[2];                     // staged W1 (2 rows, 4 cols)

  f32x4 acc[2];                     // wave tile 32 x 16 (MF=2, NF=1)
#pragma unroll
  for (int m = 0; m < 2; ++m) {
    f32x4 z = {0.f, 0.f, 0.f, 0.f};
    acc[m] = z;
  }

  auto loadT = [&](int kt) {
    const int q = kt * 16 + pl;                 // patch index
    if (q < 196) {
      const int i = q / 14, j = q - i * 14;
      const float* px = x + i * 56 + j * 2;
#pragma unroll
      for (int c = 0; c < 2; ++c) {
        const float* p = px + (size_t)(m0 + c * 32 + srow) * 784;
        atop[c] = *(const float2*)p;
        abot[c] = *(const float2*)(p + 28);
      }
    }
    const int k0 = kt * 64;
    if (k0 + kc4 < 784) {
#pragma unroll
      for (int c = 0; c < 2; ++c)
        bw[c] = *(const float4*)(W1 + (size_t)(n0 + c * 32 + srow) * 784 + k0 + kc4);
    } else {
#pragma unroll
      for (int c = 0; c < 2; ++c) bw[c] = make_float4(0.f, 0.f, 0.f, 0.f);
    }
  };

  auto writeT = [&](int buf, int kt) {
    const int q = kt * 16 + pl;
    ushort* as = As[buf];
    ushort* bs = Bs[buf];
    if (q < 196) {
#pragma unroll
      for (int c = 0; c < 2; ++c) {
        float c0 = __cosf(atop[c].x), c1 = __cosf(atop[c].y);
        float c2 = __cosf(abot[c].x), c3 = __cosf(abot[c].y);
        *(uint2*)(as + (c * 32 + srow) * LDA + pl * 4) =
            pack4(c0, c1, c0 * c2, c1 * c3);
      }
    } else {
      uint2 z; z.x = 0; z.y = 0;
#pragma unroll
      for (int c = 0; c < 2; ++c)
        *(uint2*)(as + (c * 32 + srow) * LDA + pl * 4) = z;
    }
#pragma unroll
    for (int c = 0; c < 2; ++c)
      *(uint2*)(bs + (c * 32 + srow) * LDA + kc4) =
          pack4(bw[c].x, bw[c].y, bw[c].z, bw[c].w);
  };

  auto mma = [&](int buf) {
    const ushort* as = As[buf];
    const ushort* bs = Bs[buf];
#pragma unroll
    for (int ks = 0; ks < 2; ++ks) {
      short8 af[2];
#pragma unroll
      for (int m = 0; m < 2; ++m) {
        int r = wm * 32 + m * 16 + (lane & 15);
        af[m] = *(const short8*)(as + r * LDA + ks * 32 + (lane >> 4) * 8);
      }
      int cdx = wn * 16 + (lane & 15);
      short8 bf = *(const short8*)(bs + cdx * LDA + ks * 32 + (lane >> 4) * 8);
#pragma unroll
      for (int m = 0; m < 2; ++m)
        acc[m] = __builtin_amdgcn_mfma_f32_16x16x32_bf16(af[m], bf, acc[m], 0, 0, 0);
    }
  };

  loadT(0);
  writeT(0, 0);
  __syncthreads();
  int cur = 0;
  for (int kt = 0; kt < NK; ++kt) {
    if (kt + 1 < NK) loadT(kt + 1);
    mma(cur);
    if (kt + 1 < NK) writeT(cur ^ 1, kt + 1);
    __syncthreads();
    cur ^= 1;
  }

  // C/D layout: col = lane&15, row = (lane>>4)*4 + reg   [m89-verified]
#pragma unroll
  for (int m = 0; m < 2; ++m) {
    const int colg = n0 + wn * 16 + (lane & 15);
    const float bval = b1[colg];
#pragma unroll
    for (int r = 0; r < 4; ++r) {
      const int rowg = m0 + wm * 32 + m * 16 + (lane >> 4) * 4 + r;
      h1[(size_t)rowg * 256 + colg] = f2bf(fmaxf(acc[m][r] + bval, 0.f));
    }
  }
}

// ---------------------------------------------------------------------------
// Kernel 2: h2 = relu(h1 @ W2^T + b2) -> LDS; logits = h2 @ W3^T + b3,
// log_softmax. R16: SAME grid 256 and BM=32/BN=128 (traffic-neutral vs the
// champion, unlike R13's regression) but 512 THREADS / 8 waves (2x4 wave
// grid) = 2 waves/SIMD instead of 1 — the R11->R12 lever applied here.
// ---------------------------------------------------------------------------
__global__ __launch_bounds__(512) void gemm2_head(
    const ushort* __restrict__ h1, const float* __restrict__ W2,
    const float* __restrict__ b2, const float* __restrict__ W3,
    const float* __restrict__ b3, float* __restrict__ out) {
  constexpr int LDA = 72;
  constexpr int NK = 4;   // K = 256, BK = 64
  __shared__ ushort As[2][32 * LDA];    //  9216 B
  __shared__ ushort Bs[2][128 * LDA];   // 36864 B
  __shared__ float h2f[32][132];        // 16896 B
  __shared__ float W3s[1280];           //  5120 B  (68096 total, 2 blk/CU)

  const int tid = threadIdx.x;
  const int lane = tid & 63;
  const int w = tid >> 6;               // 8 waves: 2 (rows) x 4 (cols)
  const int wm = w >> 2, wn = w & 3;
  const int m0 = blockIdx.x * 32;

  for (int i = tid; i < 1280; i += 512) W3s[i] = W3[i];

  const bool ldA = tid < 256;
  const int ar = tid >> 3, asl = tid & 7;   // A: 32 rows x 8 uint4 slots

  uint4 av;
  float4 bw[4];                             // B: 128 rows x 16 f4 slots, 4/thr

  auto loadT = [&](int kt) {
    const int k0 = kt * 64;
    if (ldA) av = *(const uint4*)(h1 + (size_t)(m0 + ar) * 256 + k0 + asl * 8);
#pragma unroll
    for (int c = 0; c < 4; ++c) {
      const int flat = c * 512 + tid, r = flat >> 4, sl = flat & 15;
      bw[c] = *(const float4*)(W2 + (size_t)r * 256 + k0 + sl * 4);
    }
  };
  auto writeT = [&](int buf) {
    if (ldA) *(uint4*)(As[buf] + ar * LDA + asl * 8) = av;
#pragma unroll
    for (int c = 0; c < 4; ++c) {
      const int flat = c * 512 + tid, r = flat >> 4, sl = flat & 15;
      *(uint2*)(Bs[buf] + r * LDA + sl * 4) =
          pack4(bw[c].x, bw[c].y, bw[c].z, bw[c].w);
    }
  };

  f32x4 acc[2];                 // wave tile 16 x 32: rows wm*16, cols wn*32
#pragma unroll
  for (int n = 0; n < 2; ++n) {
    f32x4 z = {0.f, 0.f, 0.f, 0.f};
    acc[n] = z;
  }

  auto mma = [&](int buf) {
#pragma unroll
    for (int ks = 0; ks < 2; ++ks) {
      const int r = wm * 16 + (lane & 15);
      short8 af = *(const short8*)(As[buf] + r * LDA + ks * 32 + (lane >> 4) * 8);
#pragma unroll
      for (int n = 0; n < 2; ++n) {
        const int cdx = wn * 32 + n * 16 + (lane & 15);
        short8 bf = *(const short8*)(Bs[buf] + cdx * LDA + ks * 32 + (lane >> 4) * 8);
        acc[n] = __builtin_amdgcn_mfma_f32_16x16x32_bf16(af, bf, acc[n], 0, 0, 0);
      }
    }
  };

  loadT(0);
  writeT(0);
  __syncthreads();
  int cur = 0;
#pragma unroll
  for (int kt = 0; kt < NK; ++kt) {
    if (kt + 1 < NK) loadT(kt + 1);
    mma(cur);
    if (kt + 1 < NK) writeT(cur ^ 1);
    __syncthreads();
    cur ^= 1;
  }

  // h2 tile -> LDS f32 (bias + relu)
#pragma unroll
  for (int n = 0; n < 2; ++n) {
    const int col = wn * 32 + n * 16 + (lane & 15);
    const float bval = b2[col];
#pragma unroll
    for (int r = 0; r < 4; ++r)
      h2f[wm * 16 + (lane >> 4) * 4 + r][col] = fmaxf(acc[n][r] + bval, 0.f);
  }
  __syncthreads();

  // head: 32 rows x 16 partials; k = e*16 + p (8 iters); 4-level shfl reduce
  {
    const int r = tid >> 4, p = tid & 15;
    float a10[10];
#pragma unroll
    for (int n = 0; n < 10; ++n) a10[n] = 0.f;
#pragma unroll
    for (int e = 0; e < 8; ++e) {
      const int k = e * 16 + p;
      const float hv = h2f[r][k];
#pragma unroll
      for (int n = 0; n < 10; ++n) a10[n] = fmaf(hv, W3s[n * 128 + k], a10[n]);
    }
#pragma unroll
    for (int n = 0; n < 10; ++n) {
      a10[n] += __shfl_xor(a10[n], 1);
      a10[n] += __shfl_xor(a10[n], 2);
      a10[n] += __shfl_xor(a10[n], 4);
      a10[n] += __shfl_xor(a10[n], 8);
    }
    if (p == 0) {
#pragma unroll
      for (int n = 0; n < 10; ++n) a10[n] += b3[n];
      float mx = a10[0];
#pragma unroll
      for (int n = 1; n < 10; ++n) mx = fmaxf(mx, a10[n]);
      float s = 0.f;
#pragma unroll
      for (int n = 0; n < 10; ++n) s += __expf(a10[n] - mx);
      const float lse = mx + __logf(s);
      float* po = out + (size_t)(m0 + r) * 10;
#pragma unroll
      for (int n = 0; n < 10; ++n) po[n] = a10[n] - lse;
    }
  }
}

// ---------------------------------------------------------------------------
extern "C" void kernel_launch(void* const* d_in, const int* in_sizes, int n_in,
                              void* d_out, int out_size, void* d_ws, size_t ws_size,
                              hipStream_t stream) {
  const float* x  = (const float*)d_in[0];   // (8192,1,28,28)
  // d_in[1] = params: provably unused (diagonal phases cancel in |amp|^2)
  const float* W1 = (const float*)d_in[2];
  const float* b1 = (const float*)d_in[3];
  const float* W2 = (const float*)d_in[4];
  const float* b2 = (const float*)d_in[5];
  const float* W3 = (const float*)d_in[6];
  const float* b3 = (const float*)d_in[7];
  float* out = (float*)d_out;

  ushort* h1 = (ushort*)d_ws;                 // 8192 x 256 bf16 (4.2 MB)

  hipLaunchKernelGGL(gemm1_fused, dim3(512), dim3(512), 0, stream, x, W1, b1, h1);
  hipLaunchKernelGGL(gemm2_head, dim3(256), dim3(512), 0, stream, h1, W2, b2, W3, b3, out);
}